// Round 4
// baseline (2253.386 us; speedup 1.0000x reference)
//
#include <hip/hip_runtime.h>
#include <math.h>

#define TT 1024
#define U1 128
#define U2 32

__device__ __forceinline__ float fast_tanh(float v) {
    float e = __expf(2.f * v);      // v>>0: e=inf -> 1; v<<0: e=0 -> -1 (NaN-free)
    return 1.f - 2.f / (e + 1.f);
}
__device__ __forceinline__ float fast_sig(float v) {
    return 1.f / (1.f + __expf(-v));
}
__device__ __forceinline__ float hsum4(float4 v) {
    return (v.x + v.y) + (v.z + v.w);
}

// 256 blocks x 512 threads; block owns batches {2b,2b+1}; 1 block/CU (256-VGPR cap).
// ONE barrier per step. Thread quad per GRU1 unit U=t>>2, lane role lam=t&3:
//   lam 0/1/2: full 128-long gate column (z/r/h) of unit U vs h1 (both batches).
//   lam 3, U<96 : full k2 column U vs h1 (feeds GRU2 next phase via LDS k2g).
//   lam 3, U>=96: 3 rk2 columns of u2=U-96 packed as one 128-long virtual column
//                 vs LDS [h2|h2|h2|0] replica; per-8-j4 accumulators separate the
//                 3 sums. Holds h2 state in registers; GRU2 update lagged 2 phases.
//   lam 3 also gathers z/r/h via 6 in-wave __shfl and does unit U's GRU1 update.
// Ping-pong parity: read par^1 / write par for h1s, h2rep, k2g -> single barrier.
__global__ __launch_bounds__(512, 1)
void gru_stack_kernel(const float* __restrict__ x,   // [512,1024,1]
                      const float* __restrict__ k1,  // [1,384]
                      const float* __restrict__ rk1, // [128,384]
                      const float* __restrict__ b1,  // [2,384]
                      const float* __restrict__ k2,  // [128,96]
                      const float* __restrict__ rk2, // [32,96]
                      const float* __restrict__ b2,  // [2,96]
                      const float* __restrict__ wd,  // [32,1]
                      const float* __restrict__ bd,  // [1]
                      float* __restrict__ out)       // [512,1]
{
    __shared__ __align__(16) float h1s[2][2][U1];    // [par][batch][u]
    __shared__ __align__(16) float h2rep[2][2][128]; // [par][batch][3x h2 | 0-pad]
    __shared__ __align__(16) float k2g[2][2][96];    // [par][batch][col]
    __shared__ __align__(16) float xs[2][TT];        // staged x rows
    __shared__ __align__(16) float h2fin[2][U2];

    const int t     = threadIdx.x;
    const int b0    = blockIdx.x * 2;
    const int U     = t >> 2;            // GRU1 unit 0..127
    const int lam   = t & 3;             // role within quad
    const int qbase = (t & 63) & ~3;     // wave-local quad base lane

    // ---- zero init (512 threads cover everything once) ----
    ((float*)h1s)[t]   = 0.f;            // 512 floats
    ((float*)h2rep)[t] = 0.f;            // 512 floats (incl. zero pad zone)
    if (t < 384) ((float*)k2g)[t] = 0.f;
    for (int idx = t; idx < 2 * TT; idx += 512)
        ((float*)xs)[idx] = x[b0 * TT + idx];

    // ---- weights: one 128-long (virtual) column per lane ----
    float4 w4[32];
    const bool isG2 = (lam == 3) && (U >= 96);
    if (lam < 3) {
        const int c = lam * 128 + U;     // rk1 gate column
#pragma unroll
        for (int k = 0; k < 32; ++k)
            w4[k] = make_float4(rk1[(4 * k + 0) * 384 + c], rk1[(4 * k + 1) * 384 + c],
                                rk1[(4 * k + 2) * 384 + c], rk1[(4 * k + 3) * 384 + c]);
    } else if (U < 96) {                 // k2 column U
#pragma unroll
        for (int k = 0; k < 32; ++k)
            w4[k] = make_float4(k2[(4 * k + 0) * 96 + U], k2[(4 * k + 1) * 96 + U],
                                k2[(4 * k + 2) * 96 + U], k2[(4 * k + 3) * 96 + U]);
    } else {                             // rk2 cols {u2, 32+u2, 64+u2} packed + pad
        const int u2 = U - 96;
#pragma unroll
        for (int k = 0; k < 8; ++k)
            w4[k] = make_float4(rk2[(4 * k + 0) * 96 + u2], rk2[(4 * k + 1) * 96 + u2],
                                rk2[(4 * k + 2) * 96 + u2], rk2[(4 * k + 3) * 96 + u2]);
#pragma unroll
        for (int k = 0; k < 8; ++k)
            w4[8 + k] = make_float4(rk2[(4 * k + 0) * 96 + 32 + u2], rk2[(4 * k + 1) * 96 + 32 + u2],
                                    rk2[(4 * k + 2) * 96 + 32 + u2], rk2[(4 * k + 3) * 96 + 32 + u2]);
#pragma unroll
        for (int k = 0; k < 8; ++k)
            w4[16 + k] = make_float4(rk2[(4 * k + 0) * 96 + 64 + u2], rk2[(4 * k + 1) * 96 + 64 + u2],
                                     rk2[(4 * k + 2) * 96 + 64 + u2], rk2[(4 * k + 3) * 96 + 64 + u2]);
#pragma unroll
        for (int k = 24; k < 32; ++k)
            w4[k] = make_float4(0.f, 0.f, 0.f, 0.f);
    }

    // ---- h-source pointers (parity x batch), selected per phase ----
    const float4* pb0A, *pb0B, *pb1A, *pb1B;
    if (isG2) {
        pb0A = (const float4*)&h2rep[0][0][0]; pb0B = (const float4*)&h2rep[0][1][0];
        pb1A = (const float4*)&h2rep[1][0][0]; pb1B = (const float4*)&h2rep[1][1][0];
    } else {
        pb0A = (const float4*)&h1s[0][0][0];   pb0B = (const float4*)&h1s[0][1][0];
        pb1A = (const float4*)&h1s[1][0][0];   pb1B = (const float4*)&h1s[1][1][0];
    }

    // ---- GRU1 update constants (lam==3) ----
    float k1z = 0, k1r = 0, k1h = 0, bz = 0, br = 0, bhx = 0, bhr = 0;
    float h1A = 0.f, h1B = 0.f;
    if (lam == 3) {
        k1z = k1[U]; k1r = k1[128 + U]; k1h = k1[256 + U];
        bz  = b1[U]       + b1[384 + U];
        br  = b1[128 + U] + b1[384 + 128 + U];
        bhx = b1[256 + U];
        bhr = b1[384 + 256 + U];
    }
    // ---- GRU2 constants (isG2) ----
    float bz2 = 0, br2 = 0, bh2x = 0, bh2r = 0;
    float h2A = 0.f, h2B = 0.f;
    int u2g = 0;
    if (isG2) {
        u2g  = U - 96;
        bz2  = b2[u2g]      + b2[96 + u2g];
        br2  = b2[32 + u2g] + b2[96 + 32 + u2g];
        bh2x = b2[64 + u2g];
        bh2r = b2[96 + 64 + u2g];
    }

    __syncthreads();  // init + x stage visible

    // Phase p: GRU1 step i=p (dot reads h1(p-1), update writes h1(p), p<TT).
    // GRU2 step j=p-2 (k2g read = k2*h1(j) written p-1; h2 read = h2(j-1)).
    for (int p = 0; p <= TT + 1; ++p) {
        const int wpar = p & 1;
        const int rpar = wpar ^ 1;
        const float4* pA = rpar ? pb1A : pb0A;
        const float4* pB = rpar ? pb1B : pb0B;

        float4 aA[4], aB[4];
#pragma unroll
        for (int q = 0; q < 4; ++q) {
            aA[q] = make_float4(0.f, 0.f, 0.f, 0.f);
            aB[q] = make_float4(0.f, 0.f, 0.f, 0.f);
        }
#pragma unroll
        for (int q = 0; q < 4; ++q) {
#pragma unroll
            for (int r8 = 0; r8 < 8; ++r8) {
                const int j = q * 8 + r8;
                const float4 hv = pA[j];
                const float4 wv = w4[j];
                aA[q].x = fmaf(hv.x, wv.x, aA[q].x);
                aA[q].y = fmaf(hv.y, wv.y, aA[q].y);
                aA[q].z = fmaf(hv.z, wv.z, aA[q].z);
                aA[q].w = fmaf(hv.w, wv.w, aA[q].w);
            }
        }
#pragma unroll
        for (int q = 0; q < 4; ++q) {
#pragma unroll
            for (int r8 = 0; r8 < 8; ++r8) {
                const int j = q * 8 + r8;
                const float4 hv = pB[j];
                const float4 wv = w4[j];
                aB[q].x = fmaf(hv.x, wv.x, aB[q].x);
                aB[q].y = fmaf(hv.y, wv.y, aB[q].y);
                aB[q].z = fmaf(hv.z, wv.z, aB[q].z);
                aB[q].w = fmaf(hv.w, wv.w, aB[q].w);
            }
        }

        const float4 sA4 = make_float4(aA[0].x + aA[1].x + aA[2].x + aA[3].x,
                                       aA[0].y + aA[1].y + aA[2].y + aA[3].y,
                                       aA[0].z + aA[1].z + aA[2].z + aA[3].z,
                                       aA[0].w + aA[1].w + aA[2].w + aA[3].w);
        const float4 sB4 = make_float4(aB[0].x + aB[1].x + aB[2].x + aB[3].x,
                                       aB[0].y + aB[1].y + aB[2].y + aB[3].y,
                                       aB[0].z + aB[1].z + aB[2].z + aB[3].z,
                                       aB[0].w + aB[1].w + aB[2].w + aB[3].w);
        const float sumA = hsum4(sA4);
        const float sumB = hsum4(sB4);

        // in-wave gather: quad's z/r/h dots (both batches) - unconditional shfls
        const float zA = __shfl(sumA, qbase + 0, 64);
        const float rA = __shfl(sumA, qbase + 1, 64);
        const float hA = __shfl(sumA, qbase + 2, 64);
        const float zB = __shfl(sumB, qbase + 0, 64);
        const float rB = __shfl(sumB, qbase + 1, 64);
        const float hB = __shfl(sumB, qbase + 2, 64);

        if (lam == 3) {
            if (p < TT) {
                const float xvA = xs[0][p];
                const float xvB = xs[1][p];
                // GRU1: z/r = relu, hh = tanh (reset_after)
                {
                    float z  = fmaxf(fmaf(xvA, k1z, bz) + zA, 0.f);
                    float r  = fmaxf(fmaf(xvA, k1r, br) + rA, 0.f);
                    float hh = fast_tanh(fmaf(xvA, k1h, bhx) + r * (hA + bhr));
                    h1A = fmaf(z, h1A - hh, hh);
                    h1s[wpar][0][U] = h1A;
                }
                {
                    float z  = fmaxf(fmaf(xvB, k1z, bz) + zB, 0.f);
                    float r  = fmaxf(fmaf(xvB, k1r, br) + rB, 0.f);
                    float hh = fast_tanh(fmaf(xvB, k1h, bhx) + r * (hB + bhr));
                    h1B = fmaf(z, h1B - hh, hh);
                    h1s[wpar][1][U] = h1B;
                }
            }
            if (U < 96) {
                k2g[wpar][0][U] = sumA;   // k2 . h1  (input proj for GRU2)
                k2g[wpar][1][U] = sumB;
            } else if (p >= 2) {
                // GRU2 (step p-2): z/r = sigmoid, hh = relu
                const float izA = hsum4(aA[0]), irA = hsum4(aA[1]), ihA = hsum4(aA[2]);
                const float izB = hsum4(aB[0]), irB = hsum4(aB[1]), ihB = hsum4(aB[2]);
                {
                    const float xz = k2g[rpar][0][u2g];
                    const float xr = k2g[rpar][0][32 + u2g];
                    const float xh = k2g[rpar][0][64 + u2g];
                    float z  = fast_sig(xz + izA + bz2);
                    float r  = fast_sig(xr + irA + br2);
                    float hh = fmaxf(xh + bh2x + r * (ihA + bh2r), 0.f);
                    h2A = fmaf(z, h2A - hh, hh);
                    h2rep[wpar][0][u2g]      = h2A;
                    h2rep[wpar][0][32 + u2g] = h2A;
                    h2rep[wpar][0][64 + u2g] = h2A;
                }
                {
                    const float xz = k2g[rpar][1][u2g];
                    const float xr = k2g[rpar][1][32 + u2g];
                    const float xh = k2g[rpar][1][64 + u2g];
                    float z  = fast_sig(xz + izB + bz2);
                    float r  = fast_sig(xr + irB + br2);
                    float hh = fmaxf(xh + bh2x + r * (ihB + bh2r), 0.f);
                    h2B = fmaf(z, h2B - hh, hh);
                    h2rep[wpar][1][u2g]      = h2B;
                    h2rep[wpar][1][32 + u2g] = h2B;
                    h2rep[wpar][1][64 + u2g] = h2B;
                }
            }
        }
        __syncthreads();  // the ONLY barrier per phase
    }

    if (isG2) { h2fin[0][u2g] = h2A; h2fin[1][u2g] = h2B; }
    __syncthreads();

    // ---------------- dense head ----------------
    if (t < 64) {
        const int b = t >> 5, j = t & 31;
        float pv = h2fin[b][j] * wd[j];
#pragma unroll
        for (int m = 16; m >= 1; m >>= 1) pv += __shfl_xor(pv, m, 64);
        if (j == 0) out[b0 + b] = pv + bd[0];
    }
}

extern "C" void kernel_launch(void* const* d_in, const int* in_sizes, int n_in,
                              void* d_out, int out_size, void* d_ws, size_t ws_size,
                              hipStream_t stream) {
    const float* x   = (const float*)d_in[0];
    const float* k1  = (const float*)d_in[1];
    const float* rk1 = (const float*)d_in[2];
    const float* b1  = (const float*)d_in[3];
    const float* k2  = (const float*)d_in[4];
    const float* rk2 = (const float*)d_in[5];
    const float* b2  = (const float*)d_in[6];
    const float* wd  = (const float*)d_in[7];
    const float* bd  = (const float*)d_in[8];
    float* out = (float*)d_out;

    dim3 grid(256), block(512);
    hipLaunchKernelGGL(gru_stack_kernel, grid, block, 0, stream,
                       x, k1, rk1, b1, k2, rk2, b2, wd, bd, out);
}

// Round 5
// 1779.740 us; speedup vs baseline: 1.2661x; 1.2661x over previous
//
#include <hip/hip_runtime.h>
#include <math.h>

#define TT 1024
#define U1 128
#define U2 32

__device__ __forceinline__ float fast_tanh(float v) {
    float e = __expf(2.f * v);      // v>>0: e=inf -> 1; v<<0: e=0 -> -1 (NaN-free)
    return 1.f - 2.f / (e + 1.f);
}
__device__ __forceinline__ float fast_sig(float v) {
    return 1.f / (1.f + __expf(-v));
}
__device__ __forceinline__ float hsum4(float4 v) {
    return (v.x + v.y) + (v.z + v.w);
}

// 256 blocks x 512 threads; block owns batches {2b,2b+1}; 1 block/CU.
// ONE barrier per step; all gate gathers are in-wave (shfl), not LDS.
// Mapping: quad q=t>>2 = GRU1 unit q; lane lam=t&3 owns u-quarter [32lam,32lam+32)
// of the four columns {z_q, r_q, h_q, k2col_q}: 8 broadcast b128 reads/batch,
// 32 FMA4/batch (16 FMA per read — same economics as the proven R0 dot).
// Quad-reduce via shfl_xor(1),(2); GRU1 update REPLICATED on all 4 lanes
// (h1 state in regs); lam0 writes h1 + k2 sum to parity LDS.
// GRU2 (waves 6,7 only, wave-uniform): lam<3 dot one rk2 gate-col (32-long)
// vs h2rep[rpar]; quad-shfl gather; replicated update lagged 2 phases:
//   phase p: GRU1 step p; GRU2 step j=p-2 consumes k2g[rpar]=k2*h1(p-2)
//   (written p-1) and h2rep[rpar]=h2(p-3) (written p-1). Verified vs R0 lag.
// h1p padded [4][36] so lam-quarters start on banks {0,4,8,12}: conflict-free.
__global__ __launch_bounds__(512, 1)
void gru_stack_kernel(const float* __restrict__ x,   // [512,1024,1]
                      const float* __restrict__ k1,  // [1,384]
                      const float* __restrict__ rk1, // [128,384]
                      const float* __restrict__ b1,  // [2,384]
                      const float* __restrict__ k2,  // [128,96]
                      const float* __restrict__ rk2, // [32,96]
                      const float* __restrict__ b2,  // [2,96]
                      const float* __restrict__ wd,  // [32,1]
                      const float* __restrict__ bd,  // [1]
                      float* __restrict__ out)       // [512,1]
{
    __shared__ __align__(16) float h1p[2][2][4][36]; // [par][batch][uq][32+pad]
    __shared__ __align__(16) float h2rep[2][2][U2];  // [par][batch][u2]
    __shared__ __align__(16) float k2g[2][2][96];    // [par][batch][col]
    __shared__ __align__(16) float xs[2][TT];        // staged x rows
    __shared__ __align__(16) float h2fin[2][U2];

    const int t   = threadIdx.x;
    const int q   = t >> 2;              // GRU1 unit / col-quad
    const int lam = t & 3;               // u-quarter
    const int qb  = (t & 63) & ~3;       // wave-local quad base lane
    const int b0  = blockIdx.x * 2;
    const int u2  = q - 96;              // GRU2 unit (valid t>=384)

    // ---- zero init ----
    ((float*)h1p)[t] = 0.f;                      // 576 floats total
    if (t < 64)  ((float*)h1p)[512 + t] = 0.f;
    if (t < 128) ((float*)h2rep)[t] = 0.f;
    if (t < 384) ((float*)k2g)[t] = 0.f;
    for (int idx = t; idx < 2 * TT; idx += 512)
        ((float*)xs)[idx] = x[b0 * TT + idx];

    // ---- main-dot weights: 4 cols {z,r,h,k2} of unit q over u-quarter lam ----
    float4 w4[32];
#pragma unroll
    for (int k = 0; k < 32; ++k) {
        const int u = 32 * lam + k;
        w4[k] = make_float4(rk1[u * 384 + q],
                            rk1[u * 384 + 128 + q],
                            rk1[u * 384 + 256 + q],
                            (q < 96) ? k2[u * 96 + q] : 0.f);
    }
    // ---- rk2 weights (waves 6,7; lam<3 dots gate-col 32*lam+u2) ----
    float4 wr[8];
    const bool isW67 = (t >= 384);
#pragma unroll
    for (int k = 0; k < 8; ++k) wr[k] = make_float4(0.f, 0.f, 0.f, 0.f);
    if (isW67 && lam < 3) {
        const int c = 32 * lam + u2;
#pragma unroll
        for (int k = 0; k < 8; ++k)
            wr[k] = make_float4(rk2[(4 * k + 0) * 96 + c], rk2[(4 * k + 1) * 96 + c],
                                rk2[(4 * k + 2) * 96 + c], rk2[(4 * k + 3) * 96 + c]);
    }

    // ---- GRU1 constants (per quad unit q, replicated on 4 lanes) ----
    const float k1z = k1[q], k1r = k1[128 + q], k1h = k1[256 + q];
    const float bz  = b1[q]       + b1[384 + q];
    const float br  = b1[128 + q] + b1[384 + 128 + q];
    const float bhx = b1[256 + q];
    const float bhr = b1[384 + 256 + q];
    float h1A = 0.f, h1B = 0.f;
    // ---- GRU2 constants (waves 6,7; unit u2 replicated on 4 lanes) ----
    float bz2 = 0, br2 = 0, bh2x = 0, bh2r = 0, h2A = 0.f, h2B = 0.f;
    if (isW67) {
        bz2  = b2[u2]      + b2[96 + u2];
        br2  = b2[32 + u2] + b2[96 + 32 + u2];
        bh2x = b2[64 + u2];
        bh2r = b2[96 + 64 + u2];
    }

    __syncthreads();  // init + x stage visible

    for (int p = 0; p <= TT + 1; ++p) {
        const int wpar = p & 1, rpar = wpar ^ 1;

        // ---- main dot: 4 cols of unit q vs h1(p-1), both batches ----
        const float4* pA = (const float4*)&h1p[rpar][0][lam][0];
        const float4* pB = (const float4*)&h1p[rpar][1][lam][0];
        float4 aA = make_float4(0.f, 0.f, 0.f, 0.f);
        float4 aB = make_float4(0.f, 0.f, 0.f, 0.f);
#pragma unroll
        for (int j4 = 0; j4 < 8; ++j4) {
            const float4 hvA = pA[j4];
            const float4 hvB = pB[j4];
            const float haA[4] = {hvA.x, hvA.y, hvA.z, hvA.w};
            const float haB[4] = {hvB.x, hvB.y, hvB.z, hvB.w};
#pragma unroll
            for (int e = 0; e < 4; ++e) {
                const float4 wv = w4[4 * j4 + e];
                const float hA_ = haA[e], hB_ = haB[e];
                aA.x = fmaf(hA_, wv.x, aA.x);
                aA.y = fmaf(hA_, wv.y, aA.y);
                aA.z = fmaf(hA_, wv.z, aA.z);
                aA.w = fmaf(hA_, wv.w, aA.w);
                aB.x = fmaf(hB_, wv.x, aB.x);
                aB.y = fmaf(hB_, wv.y, aB.y);
                aB.z = fmaf(hB_, wv.z, aB.z);
                aB.w = fmaf(hB_, wv.w, aB.w);
            }
        }
        // ---- quad reduce (u-quarters) : all lanes end with full sums ----
#pragma unroll
        for (int m = 1; m <= 2; m <<= 1) {
            aA.x += __shfl_xor(aA.x, m, 64);
            aA.y += __shfl_xor(aA.y, m, 64);
            aA.z += __shfl_xor(aA.z, m, 64);
            aA.w += __shfl_xor(aA.w, m, 64);
            aB.x += __shfl_xor(aB.x, m, 64);
            aB.y += __shfl_xor(aB.y, m, 64);
            aB.z += __shfl_xor(aB.z, m, 64);
            aB.w += __shfl_xor(aB.w, m, 64);
        }

        // ---- GRU1 update: replicated on all 4 lanes; lam0 writes ----
        if (p < TT) {
            const float xvA = xs[0][p];
            const float xvB = xs[1][p];
            {
                float z  = fmaxf(fmaf(xvA, k1z, bz) + aA.x, 0.f);
                float r  = fmaxf(fmaf(xvA, k1r, br) + aA.y, 0.f);
                float hh = fast_tanh(fmaf(xvA, k1h, bhx) + r * (aA.z + bhr));
                h1A = fmaf(z, h1A - hh, hh);
            }
            {
                float z  = fmaxf(fmaf(xvB, k1z, bz) + aB.x, 0.f);
                float r  = fmaxf(fmaf(xvB, k1r, br) + aB.y, 0.f);
                float hh = fast_tanh(fmaf(xvB, k1h, bhx) + r * (aB.z + bhr));
                h1B = fmaf(z, h1B - hh, hh);
            }
            if (lam == 0) {
                h1p[wpar][0][q >> 5][q & 31] = h1A;
                h1p[wpar][1][q >> 5][q & 31] = h1B;
            }
        }
        if (lam == 0 && q < 96) {       // k2 . h1(p-1) for GRU2 (parity buffer)
            k2g[wpar][0][q] = aA.w;
            k2g[wpar][1][q] = aB.w;
        }

        // ---- GRU2 (waves 6,7; wave-uniform branch) ----
        if (isW67) {
            const float4* qA = (const float4*)&h2rep[rpar][0][0];
            const float4* qB = (const float4*)&h2rep[rpar][1][0];
            float4 cA = make_float4(0.f, 0.f, 0.f, 0.f);
            float4 cB = make_float4(0.f, 0.f, 0.f, 0.f);
#pragma unroll
            for (int k = 0; k < 8; ++k) {
                const float4 hv = qA[k];
                const float4 gv = qB[k];
                const float4 wv = wr[k];
                cA.x = fmaf(hv.x, wv.x, cA.x);
                cA.y = fmaf(hv.y, wv.y, cA.y);
                cA.z = fmaf(hv.z, wv.z, cA.z);
                cA.w = fmaf(hv.w, wv.w, cA.w);
                cB.x = fmaf(gv.x, wv.x, cB.x);
                cB.y = fmaf(gv.y, wv.y, cB.y);
                cB.z = fmaf(gv.z, wv.z, cB.z);
                cB.w = fmaf(gv.w, wv.w, cB.w);
            }
            const float rsA = hsum4(cA);
            const float rsB = hsum4(cB);
            // gather gate sums across the quad (lam0=z, lam1=r, lam2=h)
            const float izA = __shfl(rsA, qb + 0, 64);
            const float irA = __shfl(rsA, qb + 1, 64);
            const float ihA = __shfl(rsA, qb + 2, 64);
            const float izB = __shfl(rsB, qb + 0, 64);
            const float irB = __shfl(rsB, qb + 1, 64);
            const float ihB = __shfl(rsB, qb + 2, 64);
            if (p >= 2) {                // GRU2 step j=p-2; replicated update
                {
                    const float xz = k2g[rpar][0][u2];
                    const float xr = k2g[rpar][0][32 + u2];
                    const float xh = k2g[rpar][0][64 + u2];
                    float z  = fast_sig(xz + izA + bz2);
                    float r  = fast_sig(xr + irA + br2);
                    float hh = fmaxf(xh + bh2x + r * (ihA + bh2r), 0.f);
                    h2A = fmaf(z, h2A - hh, hh);
                }
                {
                    const float xz = k2g[rpar][1][u2];
                    const float xr = k2g[rpar][1][32 + u2];
                    const float xh = k2g[rpar][1][64 + u2];
                    float z  = fast_sig(xz + izB + bz2);
                    float r  = fast_sig(xr + irB + br2);
                    float hh = fmaxf(xh + bh2x + r * (ihB + bh2r), 0.f);
                    h2B = fmaf(z, h2B - hh, hh);
                }
                if (lam == 0) {
                    h2rep[wpar][0][u2] = h2A;
                    h2rep[wpar][1][u2] = h2B;
                }
            }
        }
        __syncthreads();  // the ONLY barrier per phase
    }

    if (isW67 && lam == 0) { h2fin[0][u2] = h2A; h2fin[1][u2] = h2B; }
    __syncthreads();

    // ---------------- dense head ----------------
    if (t < 64) {
        const int b = t >> 5, j = t & 31;
        float pv = h2fin[b][j] * wd[j];
#pragma unroll
        for (int m = 16; m >= 1; m >>= 1) pv += __shfl_xor(pv, m, 64);
        if (j == 0) out[b0 + b] = pv + bd[0];
    }
}

extern "C" void kernel_launch(void* const* d_in, const int* in_sizes, int n_in,
                              void* d_out, int out_size, void* d_ws, size_t ws_size,
                              hipStream_t stream) {
    const float* x   = (const float*)d_in[0];
    const float* k1  = (const float*)d_in[1];
    const float* rk1 = (const float*)d_in[2];
    const float* b1  = (const float*)d_in[3];
    const float* k2  = (const float*)d_in[4];
    const float* rk2 = (const float*)d_in[5];
    const float* b2  = (const float*)d_in[6];
    const float* wd  = (const float*)d_in[7];
    const float* bd  = (const float*)d_in[8];
    float* out = (float*)d_out;

    dim3 grid(256), block(512);
    hipLaunchKernelGGL(gru_stack_kernel, grid, block, 0, stream,
                       x, k1, rk1, b1, k2, rk2, b2, wd, bd, out);
}

// Round 6
// 1410.955 us; speedup vs baseline: 1.5971x; 1.2614x over previous
//
#include <hip/hip_runtime.h>
#include <math.h>

#define TT 1024
#define U1 128
#define U2 32
#define NCOL 480   // 384 rk1 gate-cols + 96 k2 cols (both dot against h1)
#define NCP 240    // long col-pairs
#define NUQ 4      // u-quarters

__device__ __forceinline__ float fast_tanh(float v) {
    float e = __expf(2.f * v);      // v>>0: e=inf -> 1; v<<0: e=0 -> -1 (NaN-free)
    return 1.f - 2.f / (e + 1.f);
}
__device__ __forceinline__ float fast_sig(float v) {
    return 1.f / (1.f + __expf(-v));
}
__device__ __forceinline__ float hsum4(float4 v) {
    return (v.x + v.y) + (v.z + v.w);
}

// R2 structure (best: 1143us) + serial-tail surgery:
//   - x staged to LDS (xs[2][1024]) so the update phase never touches global.
//   - partials transposed: part1T[b][col][4] so the update reads 3 b128s
//     (GRU1) / 4 b128s (GRU2) instead of 12/15 serial scalar ds_reads.
// 256 blocks x 1024 threads; block owns batches {2b, 2b+1}; 1 block/CU,
// 4 waves/SIMD. Dot: thread owns 2 consecutive columns and a 32-long
// u-range; per float4 broadcast LDS read -> 8 FMAs (x2 batches).
//   t<960: cols 2p..2p+1 of [rk1|k2] vs h1 (u-quarter uq=t/240).
//   960<=t<1008: col-pairs of rk2 vs h2 (u=0..31 full).
// Update: t<256 GRU1 (h_old in reg); t 256..319 GRU2 lagged one step.
// 2 barriers/step.
__global__ __launch_bounds__(1024)
void gru_stack_kernel(const float* __restrict__ x,   // [512,1024,1]
                      const float* __restrict__ k1,  // [1,384]
                      const float* __restrict__ rk1, // [128,384]
                      const float* __restrict__ b1,  // [2,384]
                      const float* __restrict__ k2,  // [128,96]
                      const float* __restrict__ rk2, // [32,96]
                      const float* __restrict__ b2,  // [2,96]
                      const float* __restrict__ wd,  // [32,1]
                      const float* __restrict__ bd,  // [1]
                      float* __restrict__ out)       // [512,1]
{
    __shared__ __align__(16) float h1s[2][U1];
    __shared__ __align__(16) float h2s[2][U2];
    __shared__ __align__(16) float part1T[2][NCOL][4];  // [b][col][uq] - b128-readable per col
    __shared__ __align__(16) float part2T[2][U2][4];    // [b][j2][gate(3)+pad]
    __shared__ __align__(16) float xs[2][TT];           // staged x rows

    const int t  = threadIdx.x;
    const int b0 = blockIdx.x * 2;

    if (t < 2 * U1) ((float*)h1s)[t] = 0.f;
    if (t < 2 * U2) ((float*)h2s)[t] = 0.f;
    for (int idx = t; idx < 2 * TT; idx += 1024)         // coalesced x stage
        ((float*)xs)[idx] = x[b0 * TT + idx];

    // ---------------- dot-role setup ----------------
    float2 w2[32];                      // weights for 2 cols x 32 u
    const float4* pb0 = nullptr;        // h source, batch 0
    const float4* pb1 = nullptr;        // h source, batch 1
    float* pd0 = nullptr;               // partial dest, batch 0 (scalar x2)
    float* pd1 = nullptr;
    int pstride = 4;                    // float distance between col c0 and c0+1 slots
    const bool is_dot = (t < 1008);
    if (t < 960) {
        const int uq = t / NCP, p = t % NCP;
        const int c0 = 2 * p, ub = 32 * uq;
#pragma unroll
        for (int j = 0; j < 32; ++j) {
            const int u = ub + j;
            float vv[2];
#pragma unroll
            for (int r = 0; r < 2; ++r) {
                const int c = c0 + r;
                vv[r] = (c < 384) ? rk1[u * 384 + c] : k2[u * 96 + (c - 384)];
            }
            w2[j] = make_float2(vv[0], vv[1]);
        }
        pb0 = (const float4*)&h1s[0][ub];
        pb1 = (const float4*)&h1s[1][ub];
        pd0 = &part1T[0][c0][uq];
        pd1 = &part1T[1][c0][uq];
        pstride = 4;
    } else if (t < 1008) {
        const int q2 = t - 960, c0 = 2 * q2;   // rk2 cols c0, c0+1
#pragma unroll
        for (int j = 0; j < 32; ++j)
            w2[j] = make_float2(rk2[j * 96 + c0 + 0], rk2[j * 96 + c0 + 1]);
        pb0 = (const float4*)&h2s[0][0];
        pb1 = (const float4*)&h2s[1][0];
        // part2T[b][c%32][c/32]
        pd0 = &part2T[0][c0 & 31][c0 >> 5];
        pd1 = &part2T[1][c0 & 31][c0 >> 5];
        pstride = (((c0 + 1) & 31) - (c0 & 31)) * 4 + (((c0 + 1) >> 5) - (c0 >> 5));
    }

    // ---------------- update-role setup ----------------
    const int ju = t & 127, bu = t >> 7;               // t<256: GRU1 update
    float k1z = 0, k1r = 0, k1h = 0, bz = 0, br = 0, bhx = 0, bhr = 0, h_old = 0;
    if (t < 256) {
        k1z = k1[ju]; k1r = k1[128 + ju]; k1h = k1[256 + ju];
        bz  = b1[ju]       + b1[384 + ju];
        br  = b1[128 + ju] + b1[384 + 128 + ju];
        bhx = b1[256 + ju];
        bhr = b1[384 + 256 + ju];
    }
    const int tau = t - 256, j2 = tau & 31, bb2 = tau >> 5;  // t 256..319: GRU2 update
    float bz2 = 0, br2 = 0, bh2x = 0, bh2r = 0, h2_old = 0;
    if (t >= 256 && t < 320) {
        bz2  = b2[j2]      + b2[96 + j2];
        br2  = b2[32 + j2] + b2[96 + 32 + j2];
        bh2x = b2[64 + j2];
        bh2r = b2[96 + 64 + j2];
    }

    __syncthreads();  // B0: h init + x stage visible

    for (int i = 0; i <= TT; ++i) {
        if (is_dot) {
            float2 a0 = make_float2(0.f, 0.f);
            float2 a1 = make_float2(0.f, 0.f);
#pragma unroll
            for (int j4 = 0; j4 < 8; ++j4) {
                float4 hv0 = pb0[j4];
                float4 hv1 = pb1[j4];
                float ha0[4] = {hv0.x, hv0.y, hv0.z, hv0.w};
                float ha1[4] = {hv1.x, hv1.y, hv1.z, hv1.w};
#pragma unroll
                for (int e = 0; e < 4; ++e) {
                    const float2 wv = w2[4 * j4 + e];
                    const float he0 = ha0[e], he1 = ha1[e];
                    a0.x = fmaf(he0, wv.x, a0.x);
                    a0.y = fmaf(he0, wv.y, a0.y);
                    a1.x = fmaf(he1, wv.x, a1.x);
                    a1.y = fmaf(he1, wv.y, a1.y);
                }
            }
            pd0[0] = a0.x; pd0[pstride] = a0.y;
            pd1[0] = a1.x; pd1[pstride] = a1.y;
        }
        __syncthreads();  // B1: partials visible

        if (t < 256 && i < TT) {
            // GRU1 unit update: z/r = relu, hh = tanh (reset_after)
            const float xv = xs[bu][i];
            const float4 iz4 = *(const float4*)&part1T[bu][ju][0];
            const float4 ir4 = *(const float4*)&part1T[bu][128 + ju][0];
            const float4 ih4 = *(const float4*)&part1T[bu][256 + ju][0];
            float iz = hsum4(iz4);
            float ir = hsum4(ir4);
            float ih = hsum4(ih4);
            float z  = fmaxf(fmaf(xv, k1z, bz) + iz, 0.f);
            float r  = fmaxf(fmaf(xv, k1r, br) + ir, 0.f);
            float hh = fast_tanh(fmaf(xv, k1h, bhx) + r * (ih + bhr));
            h_old = fmaf(z, h_old - hh, hh);
            h1s[bu][ju] = h_old;
        } else if (t >= 256 && t < 320 && i >= 1) {
            // GRU2 unit update (one step behind): z/r = sigmoid, hh = relu
            const float4 xz4 = *(const float4*)&part1T[bb2][384 + j2][0];
            const float4 xr4 = *(const float4*)&part1T[bb2][416 + j2][0];
            const float4 xh4 = *(const float4*)&part1T[bb2][448 + j2][0];
            const float4 in4 = *(const float4*)&part2T[bb2][j2][0];
            float xz = hsum4(xz4);
            float xr = hsum4(xr4);
            float xh = hsum4(xh4);
            float z  = fast_sig(xz + in4.x + bz2);
            float r  = fast_sig(xr + in4.y + br2);
            float hh = fmaxf(xh + bh2x + r * (in4.z + bh2r), 0.f);
            h2_old = fmaf(z, h2_old - hh, hh);
            h2s[bb2][j2] = h2_old;
        }
        __syncthreads();  // B2: h updated
    }

    // ---------------- dense head ----------------
    if (t < 64) {
        const int b = t >> 5, j = t & 31;
        float p = h2s[b][j] * wd[j];
#pragma unroll
        for (int m = 16; m >= 1; m >>= 1) p += __shfl_xor(p, m, 64);
        if (j == 0) out[b0 + b] = p + bd[0];
    }
}

extern "C" void kernel_launch(void* const* d_in, const int* in_sizes, int n_in,
                              void* d_out, int out_size, void* d_ws, size_t ws_size,
                              hipStream_t stream) {
    const float* x   = (const float*)d_in[0];
    const float* k1  = (const float*)d_in[1];
    const float* rk1 = (const float*)d_in[2];
    const float* b1  = (const float*)d_in[3];
    const float* k2  = (const float*)d_in[4];
    const float* rk2 = (const float*)d_in[5];
    const float* b2  = (const float*)d_in[6];
    const float* wd  = (const float*)d_in[7];
    const float* bd  = (const float*)d_in[8];
    float* out = (float*)d_out;

    dim3 grid(256), block(1024);
    hipLaunchKernelGGL(gru_stack_kernel, grid, block, 0, stream,
                       x, k1, rk1, b1, k2, rk2, b2, wd, bd, out);
}

// Round 7
// 1140.186 us; speedup vs baseline: 1.9763x; 1.2375x over previous
//
#include <hip/hip_runtime.h>
#include <math.h>

#define TT 1024
#define U1 128
#define U2 32
#define NCOL 480   // 384 rk1 gate-cols + 96 k2 cols (both dot against h1)
#define NQ 120     // long-col quads
#define NUQ 4      // u-quarters

typedef float f2 __attribute__((ext_vector_type(2)));

// v_pk_fma_f32: D = S0*S1 + S2 on 2xf32 packed (VGPR pairs).
// PK_LO: both halves multiply by h.x  (src1 hi-half selects LO word: op_sel_hi[1]=0)
// PK_HI: both halves multiply by h.y  (both halves select HI word of src1)
#define PK_LO(acc, w, h) asm("v_pk_fma_f32 %0, %1, %2, %0 op_sel:[0,0,0] op_sel_hi:[1,0,1]" \
                             : "+v"(acc) : "v"(w), "v"(h))
#define PK_HI(acc, w, h) asm("v_pk_fma_f32 %0, %1, %2, %0 op_sel:[0,1,0] op_sel_hi:[1,1,1]" \
                             : "+v"(acc) : "v"(w), "v"(h))

__device__ __forceinline__ float fast_tanh(float v) {
    float e = __expf(2.f * v);      // v>>0: e=inf -> 1; v<<0: e=0 -> -1 (NaN-free)
    return 1.f - 2.f / (e + 1.f);
}
__device__ __forceinline__ float fast_sig(float v) {
    return 1.f / (1.f + __expf(-v));
}

// R0 structure (proven 1186us; mapping/layout/barriers identical) with:
//  (a) dot inner loop on v_pk_fma_f32: 64 pk instead of 128 plain FMAs per
//      thread-step -> dot-window becomes backend-bound (~1008 cyc) instead of
//      issue-bound (~1500 cyc).
//  (b) x staged to LDS once (xs[2][1024]) - update phase never touches global.
// 256 blocks x 512 threads; block owns batches {2b, 2b+1}; 1 block/CU.
// Dot phase (t<504): thread owns 4 consecutive columns (2 f2 col-pairs) and a
//   32-long u-range; per f2 broadcast LDS read -> 4 pk (x2 batches).
//   t<480: cols 4q..4q+3 of [rk1|k2] vs h1 (u-quarter uq=t/120).
//   480<=t<504: cols of rk2 vs h2 (u=0..31 full).
// Update phase: t<256 GRU1 unit update (h_old in reg); t 256..319 GRU2
//   update lagged one step. 2 barriers/step.
__global__ __launch_bounds__(512, 1)
void gru_stack_kernel(const float* __restrict__ x,   // [512,1024,1]
                      const float* __restrict__ k1,  // [1,384]
                      const float* __restrict__ rk1, // [128,384]
                      const float* __restrict__ b1,  // [2,384]
                      const float* __restrict__ k2,  // [128,96]
                      const float* __restrict__ rk2, // [32,96]
                      const float* __restrict__ b2,  // [2,96]
                      const float* __restrict__ wd,  // [32,1]
                      const float* __restrict__ bd,  // [1]
                      float* __restrict__ out)       // [512,1]
{
    __shared__ __align__(16) float h1s[2][U1];
    __shared__ __align__(16) float h2s[2][U2];
    __shared__ __align__(16) float part1[2][NUQ][NCOL];  // [b][uq][col]
    __shared__ __align__(16) float part2[2][96];         // rk2 partials
    __shared__ __align__(16) float xs[2][TT];            // staged x rows

    const int t  = threadIdx.x;
    const int b0 = blockIdx.x * 2;

    if (t < 2 * U1) ((float*)h1s)[t] = 0.f;
    if (t < 2 * U2) ((float*)h2s)[t] = 0.f;
    for (int idx = t; idx < 2 * TT; idx += 512)          // coalesced x stage
        ((float*)xs)[idx] = x[b0 * TT + idx];

    // ---------------- dot-role setup ----------------
    f2 wA[32], wB[32];                  // 128 VGPRs: cols {c0,c0+1} and {c0+2,c0+3} x 32 u
    const f2* pb0 = nullptr;            // h source, batch 0 (f2 pairs)
    const f2* pb1 = nullptr;            // h source, batch 1
    float4* pd0 = nullptr;              // partial dest, batch 0
    float4* pd1 = nullptr;
    const bool is_dot = (t < 504);
    if (t < 480) {
        const int uq = t / NQ, q = t % NQ;
        const int c0 = 4 * q, ub = 32 * uq;
#pragma unroll
        for (int j = 0; j < 32; ++j) {
            const int u = ub + j;
            float vv[4];
#pragma unroll
            for (int r = 0; r < 4; ++r) {
                const int c = c0 + r;
                vv[r] = (c < 384) ? rk1[u * 384 + c] : k2[u * 96 + (c - 384)];
            }
            wA[j].x = vv[0]; wA[j].y = vv[1];
            wB[j].x = vv[2]; wB[j].y = vv[3];
        }
        pb0 = (const f2*)&h1s[0][ub];
        pb1 = (const f2*)&h1s[1][ub];
        pd0 = (float4*)&part1[0][uq][c0];
        pd1 = (float4*)&part1[1][uq][c0];
    } else if (t < 504) {
        const int q2 = t - 480, c0 = 4 * q2;
#pragma unroll
        for (int j = 0; j < 32; ++j) {
            wA[j].x = rk2[j * 96 + c0 + 0]; wA[j].y = rk2[j * 96 + c0 + 1];
            wB[j].x = rk2[j * 96 + c0 + 2]; wB[j].y = rk2[j * 96 + c0 + 3];
        }
        pb0 = (const f2*)&h2s[0][0];
        pb1 = (const f2*)&h2s[1][0];
        pd0 = (float4*)&part2[0][c0];
        pd1 = (float4*)&part2[1][c0];
    }

    // ---------------- update-role setup ----------------
    const int ju = t & 127, bu = t >> 7;               // t<256: GRU1 update
    float k1z = 0, k1r = 0, k1h = 0, bz = 0, br = 0, bhx = 0, bhr = 0, h_old = 0;
    if (t < 256) {
        k1z = k1[ju]; k1r = k1[128 + ju]; k1h = k1[256 + ju];
        bz  = b1[ju]       + b1[384 + ju];
        br  = b1[128 + ju] + b1[384 + 128 + ju];
        bhx = b1[256 + ju];
        bhr = b1[384 + 256 + ju];
    }
    const int tau = t - 256, j2 = tau & 31, bb2 = tau >> 5;  // t 256..319: GRU2 update
    float bz2 = 0, br2 = 0, bh2x = 0, bh2r = 0, h2_old = 0;
    if (t >= 256 && t < 320) {
        bz2  = b2[j2]      + b2[96 + j2];
        br2  = b2[32 + j2] + b2[96 + 32 + j2];
        bh2x = b2[64 + j2];
        bh2r = b2[96 + 64 + j2];
    }

    __syncthreads();  // B0: h init + x stage visible

    for (int i = 0; i <= TT; ++i) {
        if (is_dot) {
            f2 aA0 = {0.f, 0.f}, aB0 = {0.f, 0.f};   // batch 0: cols {c0,c0+1},{c0+2,c0+3}
            f2 aA1 = {0.f, 0.f}, aB1 = {0.f, 0.f};   // batch 1
#pragma unroll
            for (int k = 0; k < 16; ++k) {
                const f2 h0 = pb0[k];                // {h[2k], h[2k+1]} batch 0
                const f2 h1 = pb1[k];                // batch 1
                PK_LO(aA0, wA[2 * k],     h0);
                PK_HI(aA0, wA[2 * k + 1], h0);
                PK_LO(aB0, wB[2 * k],     h0);
                PK_HI(aB0, wB[2 * k + 1], h0);
                PK_LO(aA1, wA[2 * k],     h1);
                PK_HI(aA1, wA[2 * k + 1], h1);
                PK_LO(aB1, wB[2 * k],     h1);
                PK_HI(aB1, wB[2 * k + 1], h1);
            }
            *pd0 = make_float4(aA0.x, aA0.y, aB0.x, aB0.y);
            *pd1 = make_float4(aA1.x, aA1.y, aB1.x, aB1.y);
        }
        __syncthreads();  // B1: partials visible

        if (t < 256 && i < TT) {
            // GRU1 unit update: z/r = relu, hh = tanh (reset_after)
            const float xv = xs[bu][i];
            float iz = part1[bu][0][ju] + part1[bu][1][ju]
                     + part1[bu][2][ju] + part1[bu][3][ju];
            float ir = part1[bu][0][128 + ju] + part1[bu][1][128 + ju]
                     + part1[bu][2][128 + ju] + part1[bu][3][128 + ju];
            float ih = part1[bu][0][256 + ju] + part1[bu][1][256 + ju]
                     + part1[bu][2][256 + ju] + part1[bu][3][256 + ju];
            float z  = fmaxf(fmaf(xv, k1z, bz) + iz, 0.f);
            float r  = fmaxf(fmaf(xv, k1r, br) + ir, 0.f);
            float hh = fast_tanh(fmaf(xv, k1h, bhx) + r * (ih + bhr));
            h_old = fmaf(z, h_old - hh, hh);
            h1s[bu][ju] = h_old;
        } else if (t >= 256 && t < 320 && i >= 1) {
            // GRU2 unit update (one step behind): z/r = sigmoid, hh = relu
            float xz = part1[bb2][0][384 + j2] + part1[bb2][1][384 + j2]
                     + part1[bb2][2][384 + j2] + part1[bb2][3][384 + j2];
            float xr = part1[bb2][0][416 + j2] + part1[bb2][1][416 + j2]
                     + part1[bb2][2][416 + j2] + part1[bb2][3][416 + j2];
            float xh = part1[bb2][0][448 + j2] + part1[bb2][1][448 + j2]
                     + part1[bb2][2][448 + j2] + part1[bb2][3][448 + j2];
            float iz = part2[bb2][j2];
            float ir = part2[bb2][32 + j2];
            float ih = part2[bb2][64 + j2];
            float z  = fast_sig(xz + iz + bz2);
            float r  = fast_sig(xr + ir + br2);
            float hh = fmaxf(xh + bh2x + r * (ih + bh2r), 0.f);
            h2_old = fmaf(z, h2_old - hh, hh);
            h2s[bb2][j2] = h2_old;
        }
        __syncthreads();  // B2: h updated
    }

    // ---------------- dense head ----------------
    if (t < 64) {
        const int b = t >> 5, j = t & 31;
        float p = h2s[b][j] * wd[j];
#pragma unroll
        for (int m = 16; m >= 1; m >>= 1) p += __shfl_xor(p, m, 64);
        if (j == 0) out[b0 + b] = p + bd[0];
    }
}

extern "C" void kernel_launch(void* const* d_in, const int* in_sizes, int n_in,
                              void* d_out, int out_size, void* d_ws, size_t ws_size,
                              hipStream_t stream) {
    const float* x   = (const float*)d_in[0];
    const float* k1  = (const float*)d_in[1];
    const float* rk1 = (const float*)d_in[2];
    const float* b1  = (const float*)d_in[3];
    const float* k2  = (const float*)d_in[4];
    const float* rk2 = (const float*)d_in[5];
    const float* b2  = (const float*)d_in[6];
    const float* wd  = (const float*)d_in[7];
    const float* bd  = (const float*)d_in[8];
    float* out = (float*)d_out;

    dim3 grid(256), block(512);
    hipLaunchKernelGGL(gru_stack_kernel, grid, block, 0, stream,
                       x, k1, rk1, b1, k2, rk2, b2, wd, bd, out);
}